// Round 1
// baseline (898.824 us; speedup 1.0000x reference)
//
#include <hip/hip_runtime.h>

typedef _Float16 f16;
typedef _Float16 f16x8 __attribute__((ext_vector_type(8)));
typedef _Float16 f16x4 __attribute__((ext_vector_type(4)));
typedef float f32x4 __attribute__((ext_vector_type(4)));

#define DIMC 1024
#define NSEQ 1024
#define NB 8
#define NH 16
#define MROWS (NB * NSEQ) /* 8192 */
#define LDQ 3072          /* qkv row stride (q|k|v concat) */

__device__ __forceinline__ f32x4 mfma16x32(f16x8 a, f16x8 b, f32x4 c) {
  return __builtin_amdgcn_mfma_f32_16x16x32_f16(a, b, c, 0, 0, 0);
}

// async global->LDS, 16B per lane; lds base must be wave-uniform (HW adds lane*16)
__device__ __forceinline__ void gload_lds16(const void* g, void* l) {
  __builtin_amdgcn_global_load_lds(
      (const __attribute__((address_space(1))) void*)g,
      (__attribute__((address_space(3))) void*)l, 16, 0, 0);
}

// ---------------- fp32 -> fp16 convert ----------------
__global__ __launch_bounds__(256) void k_convert(const float* __restrict__ src,
                                                 f16* __restrict__ dst, int n4) {
  int i = blockIdx.x * 256 + threadIdx.x;
  if (i < n4) {
    float4 v = ((const float4*)src)[i];
    f16x4 h;
    h[0] = (f16)v.x; h[1] = (f16)v.y; h[2] = (f16)v.z; h[3] = (f16)v.w;
    ((f16x4*)dst)[i] = h;
  }
}

// ---------------- GEMM: C[m,n] = A[m,:] . Bw[n,:]  (A,Bw fp16 row-major, inner dim K) ---
// F32OUT: write fp32 + bias; else fp16
template <bool F32OUT>
__global__ __launch_bounds__(256) void k_gemm(const f16* __restrict__ A,
                                              const f16* __restrict__ Bw,
                                              f16* __restrict__ Ch,
                                              float* __restrict__ Cf,
                                              const float* __restrict__ bias,
                                              int Kdim, int Ndim) {
  __shared__ __align__(16) f16 sA[128 * 32];
  __shared__ __align__(16) f16 sB[128 * 32];
  const int tid = threadIdx.x, wave = tid >> 6, lane = tid & 63;
  const int m0 = blockIdx.x * 128, n0 = blockIdx.y * 128;
  const int wm = wave >> 1, wn = wave & 1;
  const int r0 = tid >> 2, cb = (tid & 3) * 8;

  f32x4 acc[4][4];
#pragma unroll
  for (int i = 0; i < 4; ++i)
#pragma unroll
    for (int j = 0; j < 4; ++j) acc[i][j] = (f32x4){0.f, 0.f, 0.f, 0.f};

  for (int k0 = 0; k0 < Kdim; k0 += 32) {
    __syncthreads();
    gload_lds16(A + (size_t)(m0 + r0) * Kdim + k0 + cb, &sA[wave * 512]);
    gload_lds16(A + (size_t)(m0 + r0 + 64) * Kdim + k0 + cb, &sA[2048 + wave * 512]);
    gload_lds16(Bw + (size_t)(n0 + r0) * Kdim + k0 + cb, &sB[wave * 512]);
    gload_lds16(Bw + (size_t)(n0 + r0 + 64) * Kdim + k0 + cb, &sB[2048 + wave * 512]);
    __syncthreads();
    f16x8 af[4], bf[4];
#pragma unroll
    for (int mi = 0; mi < 4; ++mi)
      af[mi] = *(const f16x8*)&sA[(wm * 64 + mi * 16 + (lane & 15)) * 32 + (lane >> 4) * 8];
#pragma unroll
    for (int ni = 0; ni < 4; ++ni)
      bf[ni] = *(const f16x8*)&sB[(wn * 64 + ni * 16 + (lane & 15)) * 32 + (lane >> 4) * 8];
#pragma unroll
    for (int mi = 0; mi < 4; ++mi)
#pragma unroll
      for (int ni = 0; ni < 4; ++ni)
        acc[mi][ni] = mfma16x32(af[mi], bf[ni], acc[mi][ni]);
  }

#pragma unroll
  for (int mi = 0; mi < 4; ++mi)
#pragma unroll
    for (int ni = 0; ni < 4; ++ni) {
      int col = n0 + wn * 64 + ni * 16 + (lane & 15);
#pragma unroll
      for (int r = 0; r < 4; ++r) {
        int row = m0 + wm * 64 + mi * 16 + (lane >> 4) * 4 + r;
        if constexpr (F32OUT)
          Cf[(size_t)row * Ndim + col] = acc[mi][ni][r] + bias[col];
        else
          Ch[(size_t)row * Ndim + col] = (f16)acc[mi][ni][r];
      }
    }
}

// ---------------- trad_map: softmax over q axis of (Q Kᵀ)/8, per (b,h), 32 k-cols/WG ----
__global__ __launch_bounds__(256) void k_tradmap(const f16* __restrict__ qkv,
                                                 float* __restrict__ trad) {
  const int bh = blockIdx.x, kb = blockIdx.y;
  const int b = bh >> 4, h = bh & 15;
  const int tid = threadIdx.x, wave = tid >> 6, lane = tid & 63;
  __shared__ __align__(16) f16 sE[NSEQ * 32]; // exp(scores) tile: 64 KB
  __shared__ float sCol[4][32];
  __shared__ float sInv[32];

  const f16* Qb = qkv + (size_t)(b * NSEQ) * LDQ + h * 64;
  const f16* Kb = Qb + 1024;
  const int k0 = kb * 32;

  // K fragments (B-operand), kept in registers; same for all waves
  f16x8 bfr[2][2];
#pragma unroll
  for (int kt = 0; kt < 2; ++kt)
#pragma unroll
    for (int kh = 0; kh < 2; ++kh)
      bfr[kt][kh] = *(const f16x8*)(Kb + (size_t)(k0 + kt * 16 + (lane & 15)) * LDQ +
                                    kh * 32 + (lane >> 4) * 8);

  float cs0 = 0.f, cs1 = 0.f;
  for (int it = 0; it < 16; ++it) {
    int q0 = wave * 256 + it * 16;
    const f16* qrow = Qb + (size_t)(q0 + (lane & 15)) * LDQ + (lane >> 4) * 8;
    f16x8 a0 = *(const f16x8*)qrow;
    f16x8 a1 = *(const f16x8*)(qrow + 32);
    f32x4 acc0 = (f32x4){0.f, 0.f, 0.f, 0.f};
    f32x4 acc1 = (f32x4){0.f, 0.f, 0.f, 0.f};
    acc0 = mfma16x32(a0, bfr[0][0], acc0);
    acc0 = mfma16x32(a1, bfr[0][1], acc0);
    acc1 = mfma16x32(a0, bfr[1][0], acc1);
    acc1 = mfma16x32(a1, bfr[1][1], acc1);
    int qq = q0 + (lane >> 4) * 4;
#pragma unroll
    for (int r = 0; r < 4; ++r) {
      float e0 = __expf(acc0[r] * 0.125f);
      float e1 = __expf(acc1[r] * 0.125f);
      cs0 += e0;
      cs1 += e1;
      sE[(qq + r) * 32 + (lane & 15)] = (f16)e0;
      sE[(qq + r) * 32 + 16 + (lane & 15)] = (f16)e1;
    }
  }
  // column sums: reduce across the 4 row-groups of the wave, then across waves
  cs0 += __shfl_xor(cs0, 16); cs0 += __shfl_xor(cs0, 32);
  cs1 += __shfl_xor(cs1, 16); cs1 += __shfl_xor(cs1, 32);
  if (lane < 16) { sCol[wave][lane] = cs0; sCol[wave][16 + lane] = cs1; }
  __syncthreads();
  if (tid < 32)
    sInv[tid] = 1.0f / (sCol[0][tid] + sCol[1][tid] + sCol[2][tid] + sCol[3][tid]);
  __syncthreads();

  float* out = trad + (size_t)bh * NSEQ * NSEQ + k0;
  const int j = tid & 31, qb0 = tid >> 5;
  const float inv = sInv[j];
  for (int q = qb0; q < NSEQ; q += 8)
    out[(size_t)q * NSEQ + j] = (float)sE[q * 32 + j] * inv;
}

// ---------------- per-(b,h): kk=KᵀK+αI, ktv=KᵀV, inv, M=inv@ktv, col-softmax -> attnT ---
__global__ __launch_bounds__(256) void k_headsolve(const f16* __restrict__ qkv,
                                                   const float* __restrict__ alpha_p,
                                                   f16* __restrict__ attnT) {
  const int bh = blockIdx.x;
  const int b = bh >> 4, h = bh & 15;
  const int tid = threadIdx.x, wave = tid >> 6, lane = tid & 63;
  __shared__ __align__(16) f16 sKT[64 * 72]; // K transposed tile [d][n], padded
  __shared__ __align__(16) f16 sVT[64 * 72];
  __shared__ float kkS[64 * 66];
  __shared__ float ktvS[64 * 66];
  __shared__ float aug[64 * 130];
  __shared__ float Mx[64 * 66];
  __shared__ float cInv[64];

  const f16* Kb = qkv + (size_t)(b * NSEQ) * LDQ + 1024 + h * 64;
  const f16* Vb = Kb + 1024;

  f32x4 akk[4], akv[4];
#pragma unroll
  for (int i = 0; i < 4; ++i) {
    akk[i] = (f32x4){0.f, 0.f, 0.f, 0.f};
    akv[i] = (f32x4){0.f, 0.f, 0.f, 0.f};
  }

  for (int nt = 0; nt < 16; ++nt) {
    const int n0 = nt * 64;
    const int nn = tid & 63, dblk0 = tid >> 6;
#pragma unroll
    for (int i = 0; i < 2; ++i) {
      int dblk = dblk0 + i * 4;
      f16x8 kv = *(const f16x8*)(Kb + (size_t)(n0 + nn) * LDQ + dblk * 8);
      f16x8 vv = *(const f16x8*)(Vb + (size_t)(n0 + nn) * LDQ + dblk * 8);
#pragma unroll
      for (int j = 0; j < 8; ++j) {
        sKT[(dblk * 8 + j) * 72 + nn] = kv[j];
        sVT[(dblk * 8 + j) * 72 + nn] = vv[j];
      }
    }
    __syncthreads();
#pragma unroll
    for (int kc = 0; kc < 64; kc += 32) {
      f16x8 a = *(const f16x8*)&sKT[(wave * 16 + (lane & 15)) * 72 + kc + (lane >> 4) * 8];
#pragma unroll
      for (int ni = 0; ni < 4; ++ni) {
        f16x8 bk = *(const f16x8*)&sKT[(ni * 16 + (lane & 15)) * 72 + kc + (lane >> 4) * 8];
        akk[ni] = mfma16x32(a, bk, akk[ni]);
        f16x8 bv = *(const f16x8*)&sVT[(ni * 16 + (lane & 15)) * 72 + kc + (lane >> 4) * 8];
        akv[ni] = mfma16x32(a, bv, akv[ni]);
      }
    }
    __syncthreads();
  }

  {
    int d = wave * 16 + (lane >> 4) * 4;
#pragma unroll
    for (int ni = 0; ni < 4; ++ni)
#pragma unroll
      for (int r = 0; r < 4; ++r) {
        kkS[(d + r) * 66 + ni * 16 + (lane & 15)] = akk[ni][r];
        ktvS[(d + r) * 66 + ni * 16 + (lane & 15)] = akv[ni][r];
      }
  }
  __syncthreads();
  if (tid < 64) kkS[tid * 66 + tid] += alpha_p[0];
  __syncthreads();

  // augmented [kk | I]
  for (int idx = tid; idx < 64 * 128; idx += 256) {
    int r = idx >> 7, c = idx & 127;
    aug[r * 130 + c] = (c < 64) ? kkS[r * 66 + c] : ((c - 64) == r ? 1.f : 0.f);
  }
  __syncthreads();

  // Gauss-Jordan (SPD: no pivoting)
  const int gr = tid >> 2, gc0 = (tid & 3) * 32;
  for (int p = 0; p < 64; ++p) {
    float piv = aug[p * 130 + p];
    float f = aug[gr * 130 + p];
    __syncthreads();
    if (tid < 128) aug[p * 130 + tid] *= (1.0f / piv);
    __syncthreads();
    if (gr != p) {
#pragma unroll
      for (int c = 0; c < 32; ++c)
        aug[gr * 130 + gc0 + c] -= f * aug[p * 130 + gc0 + c];
    }
    __syncthreads();
  }

  // M = inv @ ktv ; exp
  {
    int d = tid >> 2, e0 = (tid & 3) * 16;
    float m[16];
#pragma unroll
    for (int je = 0; je < 16; ++je) m[je] = 0.f;
    for (int jj = 0; jj < 64; ++jj) {
      float fv = aug[d * 130 + 64 + jj];
#pragma unroll
      for (int je = 0; je < 16; ++je) m[je] += fv * ktvS[jj * 66 + e0 + je];
    }
#pragma unroll
    for (int je = 0; je < 16; ++je) Mx[d * 66 + e0 + je] = __expf(m[je]);
  }
  __syncthreads();
  if (tid < 64) {
    float s = 0.f;
    for (int d2 = 0; d2 < 64; ++d2) s += Mx[d2 * 66 + tid];
    cInv[tid] = 1.0f / s;
  }
  __syncthreads();
  // attnT[e][d] = softmax_d(M)[d][e]  (transposed so kernel-4 B-frags are contiguous)
  {
    int e = tid >> 2, db = (tid & 3) * 16;
    float ci = cInv[e];
#pragma unroll
    for (int j = 0; j < 16; ++j)
      attnT[(size_t)bh * 4096 + e * 64 + db + j] = (f16)(Mx[(db + j) * 66 + e] * ci);
  }
}

// ---------------- y[b,n,h*64+e] = sum_d Q[b,h,n,d] * attn[d,e] ----------------
__global__ __launch_bounds__(256) void k_yattn(const f16* __restrict__ qkv,
                                               const f16* __restrict__ attnT,
                                               f16* __restrict__ y) {
  const int bh = blockIdx.x, mb = blockIdx.y;
  const int b = bh >> 4, h = bh & 15;
  const int tid = threadIdx.x, wave = tid >> 6, lane = tid & 63;
  const f16* Qb = qkv + (size_t)(b * NSEQ) * LDQ + h * 64;
  const f16* At = attnT + (size_t)bh * 4096;

  f16x8 bf[2][4];
#pragma unroll
  for (int kc2 = 0; kc2 < 2; ++kc2)
#pragma unroll
    for (int ni = 0; ni < 4; ++ni)
      bf[kc2][ni] = *(const f16x8*)(At + (ni * 16 + (lane & 15)) * 64 + kc2 * 32 +
                                    (lane >> 4) * 8);

  const int m0 = mb * 256 + wave * 64;
  f32x4 acc[4][4];
#pragma unroll
  for (int i = 0; i < 4; ++i)
#pragma unroll
    for (int j = 0; j < 4; ++j) acc[i][j] = (f32x4){0.f, 0.f, 0.f, 0.f};

#pragma unroll
  for (int kc2 = 0; kc2 < 2; ++kc2)
#pragma unroll
    for (int mi = 0; mi < 4; ++mi) {
      f16x8 a = *(const f16x8*)(Qb + (size_t)(m0 + mi * 16 + (lane & 15)) * LDQ +
                                kc2 * 32 + (lane >> 4) * 8);
#pragma unroll
      for (int ni = 0; ni < 4; ++ni) acc[mi][ni] = mfma16x32(a, bf[kc2][ni], acc[mi][ni]);
    }

#pragma unroll
  for (int mi = 0; mi < 4; ++mi)
#pragma unroll
    for (int ni = 0; ni < 4; ++ni) {
      int col = h * 64 + ni * 16 + (lane & 15);
#pragma unroll
      for (int r = 0; r < 4; ++r) {
        int row = m0 + mi * 16 + (lane >> 4) * 4 + r;
        y[(size_t)(b * NSEQ + row) * DIMC + col] = (f16)acc[mi][ni][r];
      }
    }
}

extern "C" void kernel_launch(void* const* d_in, const int* in_sizes, int n_in,
                              void* d_out, int out_size, void* d_ws, size_t ws_size,
                              hipStream_t stream) {
  const float* x = (const float*)d_in[0];
  const float* wq = (const float*)d_in[1];
  const float* wk = (const float*)d_in[2];
  const float* wv = (const float*)d_in[3];
  const float* ow = (const float*)d_in[4];
  const float* ob = (const float*)d_in[5];
  const float* alpha = (const float*)d_in[6];

  float* outp = (float*)d_out;
  float* trad = outp + (size_t)MROWS * DIMC;

  f16* x16 = (f16*)d_ws;
  f16* w16 = x16 + (size_t)MROWS * DIMC;        // 3 stacked weights [3072,1024]
  f16* ow16 = w16 + (size_t)3 * DIMC * DIMC;
  f16* qkv = ow16 + (size_t)DIMC * DIMC;        // [8192, 3072] = q|k|v
  f16* attnT = qkv + (size_t)MROWS * 3 * DIMC;  // [128][64][64] transposed attn
  f16* y16 = attnT + (size_t)128 * 64 * 64;     // [8192, 1024]

  k_convert<<<MROWS * DIMC / 4 / 256, 256, 0, stream>>>(x, x16, MROWS * DIMC / 4);
  k_convert<<<DIMC * DIMC / 4 / 256, 256, 0, stream>>>(wq, w16, DIMC * DIMC / 4);
  k_convert<<<DIMC * DIMC / 4 / 256, 256, 0, stream>>>(wk, w16 + (size_t)DIMC * DIMC,
                                                       DIMC * DIMC / 4);
  k_convert<<<DIMC * DIMC / 4 / 256, 256, 0, stream>>>(wv, w16 + (size_t)2 * DIMC * DIMC,
                                                       DIMC * DIMC / 4);
  k_convert<<<DIMC * DIMC / 4 / 256, 256, 0, stream>>>(ow, ow16, DIMC * DIMC / 4);

  // qkv = x @ [wq;wk;wv]^T
  k_gemm<false><<<dim3(64, 24), 256, 0, stream>>>(x16, w16, qkv, nullptr, nullptr,
                                                  DIMC, 3 * DIMC);
  // trad_map
  k_tradmap<<<dim3(128, 32), 256, 0, stream>>>(qkv, trad);
  // per-head solve -> attnT
  k_headsolve<<<128, 256, 0, stream>>>(qkv, alpha, attnT);
  // y = Q @ attn
  k_yattn<<<dim3(128, 4), 256, 0, stream>>>(qkv, attnT, y16);
  // out = y @ ow^T + ob
  k_gemm<true><<<dim3(64, 8), 256, 0, stream>>>(y16, ow16, nullptr, outp, ob,
                                                DIMC, DIMC);
}